// Round 1
// baseline (200.506 us; speedup 1.0000x reference)
//
#include <hip/hip_runtime.h>
#include <stdint.h>
#include <stddef.h>

#define B_      8
#define T_      16
#define NX_     256
#define NZ_     64
#define D_      1024
#define HEADS_  8
#define DHEAD_  64
#define INNER_  512
#define NKEY_   320          // NX_ + NZ_
#define NBT_    128          // B_*T_

typedef __attribute__((ext_vector_type(8))) short     short8;
typedef __attribute__((ext_vector_type(4))) float     f32x4;
typedef __attribute__((ext_vector_type(8))) unsigned short u16x8;

__device__ __forceinline__ unsigned short f2bf(float f) {
    union { float f; unsigned int u; } v; v.f = f;
    unsigned int u = v.u;
    return (unsigned short)((u + 0x7fffu + ((u >> 16) & 1u)) >> 16);
}

// ---------------------------------------------------------------------------
// mask normalization: handles both bool-byte and int32 storage of mask[128]
// ---------------------------------------------------------------------------
__global__ void mask_kernel(const unsigned char* __restrict__ mraw,
                            int* __restrict__ maskN) {
    int lane = threadIdx.x;                 // 64 threads
    unsigned char b0 = mraw[lane];
    unsigned char b1 = mraw[lane + 64];
    // if stored as int32 (0/1), every byte at index %4!=0 is zero
    bool nz = (((lane) & 3) != 0 && b0 != 0) || (((lane + 64) & 3) != 0 && b1 != 0);
    unsigned long long ball = __ballot(nz ? 1 : 0);
    bool isBool = (ball != 0ull);
    int v0, v1;
    if (isBool) { v0 = b0; v1 = b1; }
    else        { v0 = mraw[4 * lane]; v1 = mraw[4 * (lane + 64)]; }
    maskN[lane]      = v0 ? 1 : 0;
    maskN[lane + 64] = v1 ? 1 : 0;
}

// ---------------------------------------------------------------------------
// weight prep: f32 -> bf16, transposed to [N][K] (B^T layout for MFMA B-frags)
// ---------------------------------------------------------------------------
__global__ __launch_bounds__(256) void wprep_kernel(
        const float* __restrict__ Wq, const float* __restrict__ Wkv,
        const float* __restrict__ Wo,
        unsigned short* __restrict__ WqT, unsigned short* __restrict__ WkvT,
        unsigned short* __restrict__ WoT) {
    size_t id = (size_t)blockIdx.x * 256 + threadIdx.x;
    if (id < 524288) {                       // WqT[512][1024] <- Wq[1024][512]
        int n = (int)(id >> 10), k = (int)(id & 1023);
        WqT[id] = f2bf(Wq[(size_t)k * 512 + n]);
    } else if (id < 524288 + 1048576) {      // WkvT[1024][1024] <- Wkv[1024][1024]
        size_t j = id - 524288;
        int n = (int)(j >> 10), k = (int)(j & 1023);
        WkvT[j] = f2bf(Wkv[(size_t)k * 1024 + n]);
    } else {                                 // WoT[1024][512] <- Wo[512][1024]
        size_t j = id - 1572864;
        int n = (int)(j >> 9), k = (int)(j & 511);
        WoT[j] = f2bf(Wo[(size_t)k * 1024 + n]);
    }
}

// ---------------------------------------------------------------------------
// LayerNorm rows of x (32768 rows) and latents (8192 rows) -> bf16
// one block (256 thr) per row of 1024
// ---------------------------------------------------------------------------
__global__ __launch_bounds__(256) void ln_kernel(
        const float* __restrict__ x, const float* __restrict__ lat,
        const float* __restrict__ gm, const float* __restrict__ bm,
        const float* __restrict__ gl, const float* __restrict__ bl,
        const int* __restrict__ maskN,
        unsigned short* __restrict__ xn, unsigned short* __restrict__ zn) {
    int row = blockIdx.x;
    const float* src; unsigned short* dst; const float* g; const float* b;
    int bt;
    if (row < NBT_ * NX_) {
        bt = row >> 8;
        src = x + (size_t)row * D_; dst = xn + (size_t)row * D_;
        g = gm; b = bm;
    } else {
        int r = row - NBT_ * NX_;
        bt = r >> 6;
        src = lat + (size_t)r * D_; dst = zn + (size_t)r * D_;
        g = gl; b = bl;
    }
    if (!maskN[bt]) return;                  // masked (b,t): values never read
    int t = threadIdx.x;
    float4 v = reinterpret_cast<const float4*>(src)[t];
    float s  = v.x + v.y + v.z + v.w;
    float sq = v.x * v.x + v.y * v.y + v.z * v.z + v.w * v.w;
    #pragma unroll
    for (int off = 32; off > 0; off >>= 1) {
        s  += __shfl_down(s, off);
        sq += __shfl_down(sq, off);
    }
    __shared__ float red[8];
    int wid = t >> 6;
    if ((t & 63) == 0) { red[wid] = s; red[4 + wid] = sq; }
    __syncthreads();
    float stot = red[0] + red[1] + red[2] + red[3];
    float qtot = red[4] + red[5] + red[6] + red[7];
    float mean = stot * (1.0f / 1024.0f);
    float var  = qtot * (1.0f / 1024.0f) - mean * mean;
    float rstd = rsqrtf(var + 1e-5f);
    float4 gv = reinterpret_cast<const float4*>(g)[t];
    float4 bv = reinterpret_cast<const float4*>(b)[t];
    ushort4 o;
    o.x = f2bf((v.x - mean) * rstd * gv.x + bv.x);
    o.y = f2bf((v.y - mean) * rstd * gv.y + bv.y);
    o.z = f2bf((v.z - mean) * rstd * gv.z + bv.z);
    o.w = f2bf((v.w - mean) * rstd * gv.w + bv.w);
    *reinterpret_cast<ushort4*>(dst + 4 * t) = o;
}

// ---------------------------------------------------------------------------
// batched GEMM template: C[bt] = A[bt] @ B^T   (64x64 tile, 4 waves, bf16 MFMA)
// MODE 0: q  = zn(64x1024) @ WqT(512x1024)   -> q bf16, *0.125
// MODE 1: kv = [xn;zn](320x1024) @ WkvT(1024x1024) -> k bf16 [320][512],
//                                                     vT bf16 [512][320]
// MODE 2: out = ao(64x512) @ WoT(1024x512)   -> f32 d_out (zeros if masked)
// ---------------------------------------------------------------------------
template<int MODE>
__global__ __launch_bounds__(256) void gemm_kernel(
        const unsigned short* __restrict__ xn,
        const unsigned short* __restrict__ zn,
        const unsigned short* __restrict__ ao,
        const unsigned short* __restrict__ BT,
        const int* __restrict__ maskN,
        unsigned short* __restrict__ o_q,
        unsigned short* __restrict__ o_k,
        unsigned short* __restrict__ o_v,
        float* __restrict__ o_f) {
    constexpr int K  = (MODE == 2) ? 512 : 1024;
    constexpr int TM = (MODE == 1) ? 5 : 1;
    constexpr int TN = (MODE == 0) ? 8 : 16;
    const int nwg = gridDim.x;
    int bid = (blockIdx.x & 7) * (nwg >> 3) + (blockIdx.x >> 3);  // XCD-chunked
    int bt  = bid / (TM * TN);
    int rem = bid % (TM * TN);
    int mt = rem / TN, nt = rem % TN;
    int t = threadIdx.x;
    if (!maskN[bt]) {
        if (MODE == 2) {
            int r = t >> 2, c = (t & 3) * 16;
            float4 z = make_float4(0.f, 0.f, 0.f, 0.f);
            float4* p = reinterpret_cast<float4*>(
                o_f + ((size_t)bt * 64 + r) * 1024 + nt * 64 + c);
            p[0] = z; p[1] = z; p[2] = z; p[3] = z;
        }
        return;
    }
    __shared__ __align__(16) unsigned short As[64][72];
    __shared__ __align__(16) unsigned short Bs[64][72];
    int srow = t >> 2, sc = (t & 3) * 16;
    const unsigned short* arow;
    int gr = mt * 64 + srow;
    if (MODE == 0)      arow = zn + ((size_t)bt * 64 + gr) * 1024;
    else if (MODE == 1) arow = (gr < 256) ? xn + ((size_t)bt * 256 + gr) * 1024
                                          : zn + ((size_t)bt * 64 + (gr - 256)) * 1024;
    else                arow = ao + ((size_t)bt * 64 + gr) * 512;
    const unsigned short* brow = BT + (size_t)(nt * 64 + srow) * K;

    int lane = t & 63, wid = t >> 6;
    int wm = wid >> 1, wn = wid & 1;
    int lr = lane & 15, lg = lane >> 4;

    f32x4 acc[2][2];
    #pragma unroll
    for (int i = 0; i < 2; i++)
        #pragma unroll
        for (int j = 0; j < 2; j++) acc[i][j] = (f32x4){0.f, 0.f, 0.f, 0.f};

    for (int k0 = 0; k0 < K; k0 += 64) {
        u16x8 av0 = *reinterpret_cast<const u16x8*>(arow + k0 + sc);
        u16x8 av1 = *reinterpret_cast<const u16x8*>(arow + k0 + sc + 8);
        u16x8 bv0 = *reinterpret_cast<const u16x8*>(brow + k0 + sc);
        u16x8 bv1 = *reinterpret_cast<const u16x8*>(brow + k0 + sc + 8);
        *reinterpret_cast<u16x8*>(&As[srow][sc])     = av0;
        *reinterpret_cast<u16x8*>(&As[srow][sc + 8]) = av1;
        *reinterpret_cast<u16x8*>(&Bs[srow][sc])     = bv0;
        *reinterpret_cast<u16x8*>(&Bs[srow][sc + 8]) = bv1;
        __syncthreads();
        #pragma unroll
        for (int kc = 0; kc < 2; kc++) {
            short8 a0 = *reinterpret_cast<const short8*>(&As[wm * 32 + lr][kc * 32 + lg * 8]);
            short8 a1 = *reinterpret_cast<const short8*>(&As[wm * 32 + 16 + lr][kc * 32 + lg * 8]);
            short8 b0 = *reinterpret_cast<const short8*>(&Bs[wn * 32 + lr][kc * 32 + lg * 8]);
            short8 b1 = *reinterpret_cast<const short8*>(&Bs[wn * 32 + 16 + lr][kc * 32 + lg * 8]);
            acc[0][0] = __builtin_amdgcn_mfma_f32_16x16x32_bf16(a0, b0, acc[0][0], 0, 0, 0);
            acc[0][1] = __builtin_amdgcn_mfma_f32_16x16x32_bf16(a0, b1, acc[0][1], 0, 0, 0);
            acc[1][0] = __builtin_amdgcn_mfma_f32_16x16x32_bf16(a1, b0, acc[1][0], 0, 0, 0);
            acc[1][1] = __builtin_amdgcn_mfma_f32_16x16x32_bf16(a1, b1, acc[1][1], 0, 0, 0);
        }
        __syncthreads();
    }
    #pragma unroll
    for (int mi = 0; mi < 2; mi++)
        #pragma unroll
        for (int ni = 0; ni < 2; ni++) {
            int row0 = mt * 64 + wm * 32 + mi * 16 + lg * 4;
            int col  = nt * 64 + wn * 32 + ni * 16 + lr;
            if (MODE == 1 && col >= 512) {
                // vT[512][320]: pack 4 consecutive rows into one 8B store
                ushort4 pv;
                pv.x = f2bf(acc[mi][ni][0]); pv.y = f2bf(acc[mi][ni][1]);
                pv.z = f2bf(acc[mi][ni][2]); pv.w = f2bf(acc[mi][ni][3]);
                *reinterpret_cast<ushort4*>(
                    o_v + ((size_t)bt * 512 + (col - 512)) * 320 + row0) = pv;
            } else {
                #pragma unroll
                for (int r = 0; r < 4; r++) {
                    int row = row0 + r;
                    float val = acc[mi][ni][r];
                    if (MODE == 0)
                        o_q[((size_t)bt * 64 + row) * 512 + col] = f2bf(val * 0.125f);
                    else if (MODE == 1)
                        o_k[((size_t)bt * 320 + row) * 512 + col] = f2bf(val);
                    else
                        o_f[((size_t)bt * 64 + row) * 1024 + col] = val;
                }
            }
        }
}

// ---------------------------------------------------------------------------
// fused attention per (b,t,h): sim = q @ k^T (64x320), softmax, out = attn @ v
// 4 waves, each owns 16 query rows; attn staged through LDS for PV A-frags
// ---------------------------------------------------------------------------
__global__ __launch_bounds__(256) void attn_kernel(
        const unsigned short* __restrict__ q,
        const unsigned short* __restrict__ kbuf,
        const unsigned short* __restrict__ vbuf,   // vT [bt][512][320]
        const int* __restrict__ maskN,
        unsigned short* __restrict__ ao) {
    const int nwg = gridDim.x;                     // 1024
    int bid = (blockIdx.x & 7) * (nwg >> 3) + (blockIdx.x >> 3);
    int bt = bid >> 3, h = bid & 7;
    if (!maskN[bt]) return;
    int t = threadIdx.x, w = t >> 6, lane = t & 63;
    int lr = lane & 15, lg = lane >> 4;
    __shared__ __align__(16) unsigned short attn_s[4][16][328];

    // q A-frags for this wave's 16 query rows (K = 64 -> two k-chunks)
    const unsigned short* qrow = q + ((size_t)bt * 64 + w * 16 + lr) * 512 + h * 64;
    short8 qa0 = *reinterpret_cast<const short8*>(qrow + lg * 8);
    short8 qa1 = *reinterpret_cast<const short8*>(qrow + 32 + lg * 8);

    f32x4 acc[20];
    #pragma unroll
    for (int i = 0; i < 20; i++) acc[i] = (f32x4){0.f, 0.f, 0.f, 0.f};

    const unsigned short* kb = kbuf + (size_t)bt * NKEY_ * 512 + h * 64;
    #pragma unroll
    for (int nt2 = 0; nt2 < 20; nt2++) {
        const unsigned short* krow = kb + (size_t)(nt2 * 16 + lr) * 512;
        short8 b0 = *reinterpret_cast<const short8*>(krow + lg * 8);
        short8 b1 = *reinterpret_cast<const short8*>(krow + 32 + lg * 8);
        acc[nt2] = __builtin_amdgcn_mfma_f32_16x16x32_bf16(qa0, b0, acc[nt2], 0, 0, 0);
        acc[nt2] = __builtin_amdgcn_mfma_f32_16x16x32_bf16(qa1, b1, acc[nt2], 0, 0, 0);
    }

    // row-wise softmax: row = lg*4 + r lives across the 16 lanes of group lg
    float mx[4], sm[4];
    #pragma unroll
    for (int r = 0; r < 4; r++) mx[r] = -1e30f;
    #pragma unroll
    for (int nt2 = 0; nt2 < 20; nt2++)
        #pragma unroll
        for (int r = 0; r < 4; r++) mx[r] = fmaxf(mx[r], acc[nt2][r]);
    #pragma unroll
    for (int r = 0; r < 4; r++) {
        #pragma unroll
        for (int off = 1; off < 16; off <<= 1)
            mx[r] = fmaxf(mx[r], __shfl_xor(mx[r], off));
        sm[r] = 0.f;
    }
    #pragma unroll
    for (int nt2 = 0; nt2 < 20; nt2++)
        #pragma unroll
        for (int r = 0; r < 4; r++) {
            float p = __expf(acc[nt2][r] - mx[r]);
            acc[nt2][r] = p;
            sm[r] += p;
        }
    #pragma unroll
    for (int r = 0; r < 4; r++) {
        #pragma unroll
        for (int off = 1; off < 16; off <<= 1)
            sm[r] += __shfl_xor(sm[r], off);
        sm[r] = 1.0f / sm[r];
    }
    #pragma unroll
    for (int nt2 = 0; nt2 < 20; nt2++)
        #pragma unroll
        for (int r = 0; r < 4; r++)
            attn_s[w][lg * 4 + r][nt2 * 16 + lr] = f2bf(acc[nt2][r] * sm[r]);
    __syncthreads();

    // PV: out(16x64) = attn(16x320) @ v_h(320x64); B^T = vT rows
    f32x4 o[4];
    #pragma unroll
    for (int i = 0; i < 4; i++) o[i] = (f32x4){0.f, 0.f, 0.f, 0.f};
    const unsigned short* vb = vbuf + (size_t)bt * 512 * NKEY_ + (size_t)h * 64 * NKEY_;
    #pragma unroll
    for (int kc = 0; kc < 10; kc++) {
        short8 pa = *reinterpret_cast<const short8*>(&attn_s[w][lr][kc * 32 + lg * 8]);
        #pragma unroll
        for (int ni = 0; ni < 4; ni++) {
            short8 vf = *reinterpret_cast<const short8*>(
                vb + (size_t)(ni * 16 + lr) * NKEY_ + kc * 32 + lg * 8);
            o[ni] = __builtin_amdgcn_mfma_f32_16x16x32_bf16(pa, vf, o[ni], 0, 0, 0);
        }
    }
    #pragma unroll
    for (int ni = 0; ni < 4; ni++)
        #pragma unroll
        for (int r = 0; r < 4; r++)
            ao[((size_t)bt * 64 + w * 16 + lg * 4 + r) * 512 + h * 64 + ni * 16 + lr] =
                f2bf(o[ni][r]);
}

// ---------------------------------------------------------------------------
extern "C" void kernel_launch(void* const* d_in, const int* in_sizes, int n_in,
                              void* d_out, int out_size, void* d_ws, size_t ws_size,
                              hipStream_t stream) {
    const float* x            = (const float*)d_in[0];
    const float* lat          = (const float*)d_in[1];
    const unsigned char* mraw = (const unsigned char*)d_in[2];
    const float* gm           = (const float*)d_in[3];
    const float* bm           = (const float*)d_in[4];
    const float* gl           = (const float*)d_in[5];
    const float* bl           = (const float*)d_in[6];
    const float* Wq           = (const float*)d_in[7];
    const float* Wkv          = (const float*)d_in[8];
    const float* Wo           = (const float*)d_in[9];
    float* out = (float*)d_out;

    char* ws = (char*)d_ws;
    size_t off = 0;
    int* maskN = (int*)(ws + off);             off += 1024;
    unsigned short* WqT  = (unsigned short*)(ws + off); off += 1048576;   // 512*1024*2
    unsigned short* WkvT = (unsigned short*)(ws + off); off += 2097152;   // 1024*1024*2
    unsigned short* WoT  = (unsigned short*)(ws + off); off += 1048576;   // 1024*512*2
    unsigned short* xn   = (unsigned short*)(ws + off); off += 67108864;  // 128*256*1024*2
    unsigned short* zn   = (unsigned short*)(ws + off); off += 16777216;  // 128*64*1024*2
    unsigned short* qb   = (unsigned short*)(ws + off); off += 8388608;   // 128*64*512*2
    unsigned short* kb   = (unsigned short*)(ws + off); off += 41943040;  // 128*320*512*2
    unsigned short* vb   = (unsigned short*)(ws + off); off += 41943040;  // 128*512*320*2
    unsigned short* ab   = (unsigned short*)(ws + off); off += 8388608;   // 128*64*512*2

    hipLaunchKernelGGL(mask_kernel,  dim3(1),     dim3(64),  0, stream, mraw, maskN);
    hipLaunchKernelGGL(wprep_kernel, dim3(8192),  dim3(256), 0, stream,
                       Wq, Wkv, Wo, WqT, WkvT, WoT);
    hipLaunchKernelGGL(ln_kernel,    dim3(40960), dim3(256), 0, stream,
                       x, lat, gm, bm, gl, bl, maskN, xn, zn);
    hipLaunchKernelGGL((gemm_kernel<0>), dim3(1024),  dim3(256), 0, stream,
                       xn, zn, ab, WqT,  maskN, qb, kb, vb, out);
    hipLaunchKernelGGL((gemm_kernel<1>), dim3(10240), dim3(256), 0, stream,
                       xn, zn, ab, WkvT, maskN, qb, kb, vb, out);
    hipLaunchKernelGGL(attn_kernel,      dim3(1024),  dim3(256), 0, stream,
                       qb, kb, vb, maskN, ab);
    hipLaunchKernelGGL((gemm_kernel<2>), dim3(2048),  dim3(256), 0, stream,
                       xn, zn, ab, WoT,  maskN, qb, kb, vb, out);
}